// Round 15
// baseline (550.049 us; speedup 1.0000x reference)
//
#include <hip/hip_runtime.h>

#define E_NUM 12000
#define D_DIM 6272
#define H_DIM 256
#define M1 24000

typedef __attribute__((ext_vector_type(8))) short short8;
typedef __attribute__((ext_vector_type(8))) __bf16 bf16x8;
typedef __attribute__((ext_vector_type(4))) float f32x4;

__device__ __forceinline__ float silu_f(float x) {
  return x / (1.0f + __expf(-x));
}

__device__ __forceinline__ bf16x8 ld_frag(const short* p) {
  return __builtin_bit_cast(bf16x8, *(const short8*)p);
}

__device__ __forceinline__ bf16x8 cvt8(f32x4 a, f32x4 b) {
  bf16x8 r;
#pragma unroll
  for (int j = 0; j < 4; ++j) {
    r[j] = (__bf16)a[j];
    r[4 + j] = (__bf16)b[j];
  }
  return r;
}

__device__ __forceinline__ void gll16(const void* g, void* l) {
  __builtin_amdgcn_global_load_lds(
      (const __attribute__((address_space(1))) void*)g,
      (__attribute__((address_space(3))) void*)l, 16, 0, 0);
}

// ---- P1 pack: P1[(kt*256 + col)*32 + p] = bf(W1[kt*32 + p][col]) ----
__global__ void pack_p1(const float* __restrict__ W1, short* __restrict__ P1) {
  const int kt = blockIdx.x;    // 0..195
  const int col = threadIdx.x;  // 0..255
  const float* src = W1 + (size_t)kt * 32 * H_DIM + col;
  short* dst = P1 + ((size_t)kt * H_DIM + col) * 32;
#pragma unroll
  for (int c = 0; c < 4; ++c) {
    short8 s;
#pragma unroll
    for (int j = 0; j < 8; ++j)
      s[j] = __builtin_bit_cast(short, (__bf16)src[(size_t)(c * 8 + j) * H_DIM]);
    *(short8*)(dst + c * 8) = s;
  }
}

// ---- P2 pack: P2[(kt*D_DIM + col)*32 + p] = bf(W2[kt*32 + p][col]) ----
__global__ void pack_p2(const float* __restrict__ W2, short* __restrict__ P2) {
  const int kt = blockIdx.y;                       // 0..7
  const int col = blockIdx.x * 128 + threadIdx.x;  // 0..6271
  const float* src = W2 + (size_t)kt * 32 * D_DIM + col;
  short* dst = P2 + ((size_t)kt * D_DIM + col) * 32;
#pragma unroll
  for (int c = 0; c < 4; ++c) {
    short8 s;
#pragma unroll
    for (int j = 0; j < 8; ++j)
      s[j] = __builtin_bit_cast(short, (__bf16)src[(size_t)(c * 8 + j) * D_DIM]);
    *(short8*)(dst + c * 8) = s;
  }
}

// ========= GEMM1 v10b: counted-vmcnt pipeline (T3+T4). BM=32 BN=256 BK=32, 3 bufs =========
// Per-wave glls per tile L=5 (1 A + 4 B). Steady wait vmcnt(5): tile `it` landed
// (per-wave in-order retirement); tile it+1 stays in flight ACROSS the raw s_barrier.
// Each wave waits for its OWN tile-i glls; the barrier then guarantees ALL waves'.
#define G1_NT 196
__launch_bounds__(256, 2)
__global__ void gemm1_kernel(const float* __restrict__ node_embed,
                             const float* __restrict__ ori,
                             const float* __restrict__ x_edge_c,
                             const short* __restrict__ P1,
                             const float* __restrict__ b1,
                             short* __restrict__ hgp) {
  __shared__ __align__(16) float Abuf[3][32 * 32];   // 3 x 4 KB
  __shared__ __align__(16) short Bbuf[3][256 * 32];  // 3 x 16 KB

  const int t = threadIdx.x;
  const int wn = t >> 6;
  const int lane = t & 63;
  const int l15 = lane & 15;
  const int lq = lane >> 4;
  const int m_base = blockIdx.x * 32;

  // A staging: thread t -> dest 16B at float idx t*4 (row ar=t>>3, phys chunk t&7);
  // source logical chunk ag = (t&7)^(ar&7)  => logical g stored at phys g^(r&7).
  const int ar = t >> 3;
  const int ag = (t & 7) ^ (ar & 7);
  const float* xb = (m_base < E_NUM) ? (node_embed + (size_t)m_base * D_DIM)
                                     : (ori + (size_t)(m_base - E_NUM) * D_DIM);
  const float* asrc = xb + (size_t)ar * D_DIM + ag * 4;  // + it*32 floats

  // B staging: j=0..3: dest short t*8 + j*2048 (col cl=(t>>2)+j*64, phys chunk t&3);
  // source logical chunk g=(t&3)^(cl&3). P1 tile it at +it*8192 shorts.
  const short* bsrc[4];
#pragma unroll
  for (int j = 0; j < 4; ++j) {
    const int cl = (t >> 2) + j * 64;
    const int g = (t & 3) ^ (cl & 3);
    bsrc[j] = P1 + (size_t)cl * 32 + g * 8;
  }

  f32x4 acc[2][4];
#pragma unroll
  for (int m = 0; m < 2; ++m)
#pragma unroll
    for (int n = 0; n < 4; ++n) acc[m][n] = (f32x4){0.f, 0.f, 0.f, 0.f};

#define G1_STAGE(IT, BUF)                                                   \
  do {                                                                      \
    gll16(asrc + (size_t)(IT) * 32, &Abuf[BUF][t * 4]);                     \
    const size_t _bo = (size_t)(IT) * 8192;                                 \
    gll16(bsrc[0] + _bo, &Bbuf[BUF][t * 8]);                                \
    gll16(bsrc[1] + _bo, &Bbuf[BUF][t * 8 + 2048]);                         \
    gll16(bsrc[2] + _bo, &Bbuf[BUF][t * 8 + 4096]);                         \
    gll16(bsrc[3] + _bo, &Bbuf[BUF][t * 8 + 6144]);                         \
  } while (0)

#define G1_COMPUTE(BUF)                                                     \
  do {                                                                      \
    const float* Ap = &Abuf[BUF][0];                                        \
    const short* Bp = &Bbuf[BUF][0];                                        \
    bf16x8 af[2];                                                           \
    _Pragma("unroll") for (int m = 0; m < 2; ++m) {                         \
      const int r = m * 16 + l15;                                           \
      f32x4 lo = *(const f32x4*)(Ap + r * 32 + (((2 * lq) ^ (l15 & 7)) * 4)); \
      f32x4 hi = *(const f32x4*)(Ap + r * 32 + (((2 * lq + 1) ^ (l15 & 7)) * 4)); \
      af[m] = cvt8(lo, hi);                                                 \
    }                                                                       \
    bf16x8 bq[4];                                                           \
    _Pragma("unroll") for (int n = 0; n < 4; ++n) {                         \
      const int col = wn * 64 + n * 16 + l15;                               \
      bq[n] = ld_frag(Bp + col * 32 + ((lq ^ (col & 3)) * 8));              \
    }                                                                       \
    _Pragma("unroll") for (int m = 0; m < 2; ++m)                           \
      _Pragma("unroll") for (int n = 0; n < 4; ++n)                         \
        acc[m][n] = __builtin_amdgcn_mfma_f32_16x16x32_bf16(af[m], bq[n],   \
                                                            acc[m][n], 0, 0, 0); \
  } while (0)

  // prologue: tiles 0,1 in flight (10 outstanding)
  G1_STAGE(0, 0);
  G1_STAGE(1, 1);

  int bsel = 0;
  for (int it = 0; it < G1_NT - 1; ++it) {
    asm volatile("s_waitcnt vmcnt(5)" ::: "memory");
    __builtin_amdgcn_sched_barrier(0);
    __builtin_amdgcn_s_barrier();
    __builtin_amdgcn_sched_barrier(0);
    G1_COMPUTE(bsel);
    if (it + 2 < G1_NT) {
      const int nb = (bsel + 2) % 3;
      G1_STAGE(it + 2, nb);
    }
    bsel = (bsel == 2) ? 0 : bsel + 1;
  }
  asm volatile("s_waitcnt vmcnt(0)" ::: "memory");
  __builtin_amdgcn_sched_barrier(0);
  __builtin_amdgcn_s_barrier();
  __builtin_amdgcn_sched_barrier(0);
  G1_COMPUTE(bsel);

  // epilogue: bias + silu + gate -> hgp panel layout [8][24000][32]
#pragma unroll
  for (int n = 0; n < 4; ++n) {
    const int col = wn * 64 + n * 16 + l15;
    const float b1v = b1[col];
    const int panel = wn * 2 + (n >> 1);
    const int cin = (n & 1) * 16 + l15;
#pragma unroll
    for (int m = 0; m < 2; ++m) {
#pragma unroll
      for (int i = 0; i < 4; ++i) {
        const int gmr = m_base + m * 16 + lq * 4 + i;
        const int e = (gmr < E_NUM) ? gmr : gmr - E_NUM;
        float v = acc[m][n][i] + b1v;
        v = silu_f(v) * x_edge_c[(size_t)e * H_DIM + col];
        hgp[((size_t)panel * M1 + gmr) * 32 + cin] = __builtin_bit_cast(short, (__bf16)v);
      }
    }
  }
#undef G1_STAGE
#undef G1_COMPUTE
}

// ========= GEMM2 v8b: counted-vmcnt, OOB FIXED (+2048 not +4096). 128 A-rows x 128 d ====
#define G2_NT 8
__launch_bounds__(256, 3)
__global__ void gemm2_kernel(const short* __restrict__ hgp,
                             const short* __restrict__ P2,
                             const float* __restrict__ b2,
                             float* __restrict__ out) {
  __shared__ __align__(16) short Abuf[3][128 * 32];  // 3 x 8 KB (4096 shorts each)
  __shared__ __align__(16) short Bbuf[3][128 * 32];  // 3 x 8 KB

  const int t = threadIdx.x;
  const int wd = t >> 6;  // wave -> 32 d-cols
  const int lane = t & 63;
  const int l15 = lane & 15;
  const int lq = lane >> 4;
  const int d0 = blockIdx.x * 128;
  const int e0 = blockIdx.y * 64;

  // staging: j=0/1: dest short t*8 + j*2048 -> row (t>>2)+64j, phys chunk t&3
  const int sr = t >> 2;
  const short* asrc[2];
  const short* bsrc[2];
#pragma unroll
  for (int j = 0; j < 2; ++j) {
    const int row = sr + j * 64;
    const int g = (t & 3) ^ (row & 3);
    int e = e0 + sr;
    if (e >= E_NUM) e = E_NUM - 1;  // clamped rows never stored
    const int grow = (j == 0) ? e : (E_NUM + e);
    asrc[j] = hgp + (size_t)grow * 32 + g * 8;       // + it*(M1*32)
    bsrc[j] = P2 + (size_t)(d0 + row) * 32 + g * 8;  // + it*(D_DIM*32)
  }

  f32x4 acc[8][2];
#pragma unroll
  for (int m = 0; m < 8; ++m)
#pragma unroll
    for (int n = 0; n < 2; ++n) acc[m][n] = (f32x4){0.f, 0.f, 0.f, 0.f};

#define G2_STAGE(IT, BUF)                                                   \
  do {                                                                      \
    const size_t _ka = (size_t)(IT) * (M1 * 32);                            \
    const size_t _kb = (size_t)(IT) * ((size_t)D_DIM * 32);                 \
    gll16(asrc[0] + _ka, &Abuf[BUF][t * 8]);                                \
    gll16(asrc[1] + _ka, &Abuf[BUF][t * 8 + 2048]);                         \
    gll16(bsrc[0] + _kb, &Bbuf[BUF][t * 8]);                                \
    gll16(bsrc[1] + _kb, &Bbuf[BUF][t * 8 + 2048]);                         \
  } while (0)

#define G2_COMPUTE(BUF)                                                     \
  do {                                                                      \
    const short* Ap = &Abuf[BUF][0];                                        \
    const short* Bp = &Bbuf[BUF][0];                                        \
    bf16x8 bq[2];                                                           \
    _Pragma("unroll") for (int n = 0; n < 2; ++n) {                         \
      const int cl = wd * 32 + n * 16 + l15;                                \
      bq[n] = ld_frag(Bp + cl * 32 + ((lq ^ (cl & 3)) * 8));                \
    }                                                                       \
    _Pragma("unroll") for (int m = 0; m < 8; ++m) {                         \
      const int r = m * 16 + l15;                                           \
      bf16x8 af = ld_frag(Ap + r * 32 + ((lq ^ (l15 & 3)) * 8));            \
      _Pragma("unroll") for (int n = 0; n < 2; ++n)                         \
        acc[m][n] = __builtin_amdgcn_mfma_f32_16x16x32_bf16(af, bq[n],      \
                                                            acc[m][n], 0, 0, 0); \
    }                                                                       \
  } while (0)

  G2_STAGE(0, 0);
  G2_STAGE(1, 1);

  int bsel = 0;
  for (int it = 0; it < G2_NT - 1; ++it) {
    asm volatile("s_waitcnt vmcnt(4)" ::: "memory");
    __builtin_amdgcn_sched_barrier(0);
    __builtin_amdgcn_s_barrier();
    __builtin_amdgcn_sched_barrier(0);
    G2_COMPUTE(bsel);
    if (it + 2 < G2_NT) {
      const int nb = (bsel + 2) % 3;
      G2_STAGE(it + 2, nb);
    }
    bsel = (bsel == 2) ? 0 : bsel + 1;
  }
  asm volatile("s_waitcnt vmcnt(0)" ::: "memory");
  __builtin_amdgcn_sched_barrier(0);
  __builtin_amdgcn_s_barrier();
  __builtin_amdgcn_sched_barrier(0);
  G2_COMPUTE(bsel);

  // epilogue: bias + silu + combine halves -> fp32 out
#pragma unroll
  for (int n = 0; n < 2; ++n) {
    const int col = d0 + wd * 32 + n * 16 + l15;
    const float b2v = b2[col];
#pragma unroll
    for (int mm = 0; mm < 4; ++mm) {
#pragma unroll
      for (int i = 0; i < 4; ++i) {
        const int e = e0 + mm * 16 + lq * 4 + i;
        if (e < E_NUM) {
          out[(size_t)e * D_DIM + col] =
              silu_f(acc[mm][n][i] + b2v) + silu_f(acc[mm + 4][n][i] + b2v);
        }
      }
    }
  }
#undef G2_STAGE
#undef G2_COMPUTE
}

extern "C" void kernel_launch(void* const* d_in, const int* in_sizes, int n_in,
                              void* d_out, int out_size, void* d_ws, size_t ws_size,
                              hipStream_t stream) {
  const float* node_embed = (const float*)d_in[0];
  const float* x_edge_c = (const float*)d_in[1];
  const float* ori = (const float*)d_in[2];
  const float* W1 = (const float*)d_in[3];
  const float* b1 = (const float*)d_in[4];
  const float* W2 = (const float*)d_in[5];
  const float* b2 = (const float*)d_in[6];
  float* out_p = (float*)d_out;

  char* ws = (char*)d_ws;
  short* P1 = (short*)ws;                   // [196][256][32] bf16 = 3,211,264 B
  short* P2 = (short*)(ws + 3211264);       // [8][6272][32] bf16 = 3,211,264 B
  short* hgp = (short*)(ws + 2 * 3211264);  // [8][24000][32] bf16 = 12,288,000 B

  pack_p1<<<dim3(D_DIM / 32), 256, 0, stream>>>(W1, P1);
  pack_p2<<<dim3(D_DIM / 128, 8), 128, 0, stream>>>(W2, P2);

  gemm1_kernel<<<dim3(M1 / 32), 256, 0, stream>>>(node_embed, ori, x_edge_c, P1, b1, hgp);

  gemm2_kernel<<<dim3(D_DIM / 128, (E_NUM + 63) / 64), 256, 0, stream>>>(hgp, P2, b2, out_p);
}

// Round 16
// 445.048 us; speedup vs baseline: 1.2359x; 1.2359x over previous
//
#include <hip/hip_runtime.h>

#define E_NUM 12000
#define D_DIM 6272
#define H_DIM 256
#define M1 24000

typedef __attribute__((ext_vector_type(8))) short short8;
typedef __attribute__((ext_vector_type(8))) __bf16 bf16x8;
typedef __attribute__((ext_vector_type(4))) float f32x4;

__device__ __forceinline__ float silu_f(float x) {
  return x / (1.0f + __expf(-x));
}

__device__ __forceinline__ bf16x8 ld_frag(const short* p) {
  return __builtin_bit_cast(bf16x8, *(const short8*)p);
}

__device__ __forceinline__ bf16x8 cvt8(f32x4 a, f32x4 b) {
  bf16x8 r;
#pragma unroll
  for (int j = 0; j < 4; ++j) {
    r[j] = (__bf16)a[j];
    r[4 + j] = (__bf16)b[j];
  }
  return r;
}

__device__ __forceinline__ void gll16(const void* g, void* l) {
  __builtin_amdgcn_global_load_lds(
      (const __attribute__((address_space(1))) void*)g,
      (__attribute__((address_space(3))) void*)l, 16, 0, 0);
}

// ---- P1 pack: P1[(kt*256 + col)*32 + p] = bf(W1[kt*32 + p][col]) ----
__global__ void pack_p1(const float* __restrict__ W1, short* __restrict__ P1) {
  const int kt = blockIdx.x;    // 0..195
  const int col = threadIdx.x;  // 0..255
  const float* src = W1 + (size_t)kt * 32 * H_DIM + col;
  short* dst = P1 + ((size_t)kt * H_DIM + col) * 32;
#pragma unroll
  for (int c = 0; c < 4; ++c) {
    short8 s;
#pragma unroll
    for (int j = 0; j < 8; ++j)
      s[j] = __builtin_bit_cast(short, (__bf16)src[(size_t)(c * 8 + j) * H_DIM]);
    *(short8*)(dst + c * 8) = s;
  }
}

// ---- P2 pack: P2[(kt*D_DIM + col)*32 + p] = bf(W2[kt*32 + p][col]) ----
__global__ void pack_p2(const float* __restrict__ W2, short* __restrict__ P2) {
  const int kt = blockIdx.y;                       // 0..7
  const int col = blockIdx.x * 128 + threadIdx.x;  // 0..6271
  const float* src = W2 + (size_t)kt * 32 * D_DIM + col;
  short* dst = P2 + ((size_t)kt * D_DIM + col) * 32;
#pragma unroll
  for (int c = 0; c < 4; ++c) {
    short8 s;
#pragma unroll
    for (int j = 0; j < 8; ++j)
      s[j] = __builtin_bit_cast(short, (__bf16)src[(size_t)(c * 8 + j) * D_DIM]);
    *(short8*)(dst + c * 8) = s;
  }
}

// ====== GEMM1 v14: v13 tile (BM=32, BN=256, BK=128) but 512 thr / 8 waves ======
// Wave wn owns 32 of the 256 cols -> ~23 waves/CU (73% occupancy) at grid 750.
// Same LDS (2x16KB), same staging bytes, same swizzles as the proven v13.
#define G1_NT 49
__launch_bounds__(512, 6)
__global__ void gemm1_kernel(const float* __restrict__ node_embed,
                             const float* __restrict__ ori,
                             const float* __restrict__ x_edge_c,
                             const short* __restrict__ P1,
                             const float* __restrict__ b1,
                             short* __restrict__ hgp) {
  __shared__ __align__(16) float Abuf[2][32 * 128];  // 2 x 16 KB

  const int t = threadIdx.x;   // 0..511
  const int wn = t >> 6;       // 0..7 -> 32-col slice
  const int lane = t & 63;
  const int l15 = lane & 15;
  const int lq = lane >> 4;
  const int m_base = blockIdx.x * 32;

  const float* xb = (m_base < E_NUM) ? (node_embed + (size_t)m_base * D_DIM)
                                     : (ori + (size_t)(m_base - E_NUM) * D_DIM);

  // staging: 2 rounds; round r: dest float idx = t*4 + r*2048 -> row (t>>5)+16r,
  // phys chunk t&31; logical chunk = (t&24)|((t&7)^((t>>5)&7)) (row&7 invariant).
  const float* aP = xb + (size_t)(t >> 5) * D_DIM +
                    (((t & 24) | ((t & 7) ^ ((t >> 5) & 7))) * 4);

  // B fragment base: col = wn*32 + n*16 + l15 (n=0,1), k-slot lq*8 -> 1KB frags
  const short* bbase = P1 + (size_t)(wn * 32 + l15) * 32 + lq * 8;

  const int asw = l15 & 7;

  f32x4 acc[2][2];
#pragma unroll
  for (int m = 0; m < 2; ++m)
#pragma unroll
    for (int n = 0; n < 2; ++n) acc[m][n] = (f32x4){0.f, 0.f, 0.f, 0.f};

#define G1_STAGE(IT, BUF)                                        \
  do {                                                           \
    const float* _a = aP + (size_t)(IT)*128;                     \
    gll16(_a, &Abuf[BUF][t * 4]);                                \
    gll16(_a + (size_t)16 * D_DIM, &Abuf[BUF][t * 4 + 2048]);    \
  } while (0)

  G1_STAGE(0, 0);
  __syncthreads();

  int cur = 0;
  for (int it = 0; it < G1_NT; ++it) {
    const int nxt = cur ^ 1;

    // B frags for this mega-step: 4 kt-tiles x 2 n (1KB contiguous each, L2)
    bf16x8 bq[4][2];
    {
      const short* bs = bbase + (size_t)it * 32768;
#pragma unroll
      for (int ks = 0; ks < 4; ++ks)
#pragma unroll
        for (int n = 0; n < 2; ++n) bq[ks][n] = ld_frag(bs + ks * 8192 + n * 512);
    }

    if (it + 1 < G1_NT) G1_STAGE(it + 1, nxt);

    const float* Ap = &Abuf[cur][0];
#pragma unroll
    for (int ks = 0; ks < 4; ++ks) {
      bf16x8 af[2];
#pragma unroll
      for (int m = 0; m < 2; ++m) {
        const int row = m * 16 + l15;
        const int c_lo = 8 * ks + 2 * lq;
        const int pl = (c_lo & 24) | ((c_lo & 7) ^ asw);
        const int ph = (c_lo & 24) | (((c_lo + 1) & 7) ^ asw);
        f32x4 lo = *(const f32x4*)(Ap + row * 128 + pl * 4);
        f32x4 hi = *(const f32x4*)(Ap + row * 128 + ph * 4);
        af[m] = cvt8(lo, hi);
      }
#pragma unroll
      for (int m = 0; m < 2; ++m)
#pragma unroll
        for (int n = 0; n < 2; ++n)
          acc[m][n] = __builtin_amdgcn_mfma_f32_16x16x32_bf16(af[m], bq[ks][n],
                                                              acc[m][n], 0, 0, 0);
    }
    __syncthreads();
    cur = nxt;
  }

  // epilogue: bias + silu + gate -> hgp panel layout [8][24000][32]
#pragma unroll
  for (int n = 0; n < 2; ++n) {
    const int col = wn * 32 + n * 16 + l15;
    const float b1v = b1[col];
    const int cin = n * 16 + l15;
#pragma unroll
    for (int m = 0; m < 2; ++m) {
#pragma unroll
      for (int i = 0; i < 4; ++i) {
        const int gmr = m_base + m * 16 + lq * 4 + i;
        const int e = (gmr < E_NUM) ? gmr : gmr - E_NUM;
        float v = acc[m][n][i] + b1v;
        v = silu_f(v) * x_edge_c[(size_t)e * H_DIM + col];
        hgp[((size_t)wn * M1 + gmr) * 32 + cin] = __builtin_bit_cast(short, (__bf16)v);
      }
    }
  }
#undef G1_STAGE
}

// ====== GEMM2 (R7/R13's proven v5): m97-structure, gll A, direct B ======
// out[e] = silu(hg[e]@W2+b2) + silu(hg[e+E]@W2+b2)
// 64 e-rows (+64 mirrored) x 128 d-cols; K=256, BK=64 (4 steps); 256 thr, 4 waves 2x2.
__launch_bounds__(256, 3)
__global__ void gemm2_kernel(const short* __restrict__ hgp,
                             const short* __restrict__ P2,
                             const float* __restrict__ b2,
                             float* __restrict__ out) {
  __shared__ __align__(16) short Als[2][128 * 64];  // 2 x 16 KB

  const int t = threadIdx.x;
  const int wave = t >> 6;
  const int lane = t & 63;
  const int l15 = lane & 15;
  const int lq = lane >> 4;
  const int wr = wave >> 1;  // e-row half (32 rows)
  const int wc = wave & 1;   // d-col half (64 cols)
  const int d0 = blockIdx.x * 128;
  const int e0 = blockIdx.y * 64;

  // staging: round r (0..3): dest short idx = t*8 + r*2048 -> row R=(t>>3)+r*32, chunk=t&7
  const int R0 = t >> 3;  // 0..31
  const int cst = t & 7;
  const int cl = cst ^ (R0 & 7);
  const short* asrc[4];
#pragma unroll
  for (int r = 0; r < 4; ++r) {
    int er = e0 + R0 + (r & 1) * 32;
    if (er >= E_NUM) er = E_NUM - 1;
    const int grow = er + (r >> 1) * E_NUM;
    asrc[r] = hgp + (size_t)(cl >> 2) * (M1 * 32) + (size_t)grow * 32 + (cl & 3) * 8;
  }

  const short* bbase = P2 + (size_t)(d0 + wc * 64 + l15) * 32 + lq * 8;
  const int asw = l15 & 7;

  f32x4 acc[2][2][4];
#pragma unroll
  for (int h = 0; h < 2; ++h)
#pragma unroll
    for (int m = 0; m < 2; ++m)
#pragma unroll
      for (int n = 0; n < 4; ++n) acc[h][m][n] = (f32x4){0.f, 0.f, 0.f, 0.f};

  // prologue: stage k-step 0
#pragma unroll
  for (int r = 0; r < 4; ++r) gll16(asrc[r], &Als[0][t * 8 + r * 2048]);
  __syncthreads();

  int cur = 0;
#pragma unroll
  for (int it = 0; it < 4; ++it) {
    const int nxt = cur ^ 1;
    if (it < 3) {
      const size_t ko = (size_t)(it + 1) * 2 * (M1 * 32);
#pragma unroll
      for (int r = 0; r < 4; ++r) gll16(asrc[r] + ko, &Als[nxt][t * 8 + r * 2048]);
    }
    bf16x8 bq[2][4];
#pragma unroll
    for (int ks = 0; ks < 2; ++ks)
#pragma unroll
      for (int n = 0; n < 4; ++n)
        bq[ks][n] = ld_frag(bbase + (size_t)(it * 2 + ks) * (D_DIM * 32) + n * 512);

    bf16x8 af[2][2][2];
#pragma unroll
    for (int h = 0; h < 2; ++h)
#pragma unroll
      for (int m = 0; m < 2; ++m)
#pragma unroll
        for (int ks = 0; ks < 2; ++ks) {
          const int R = h * 64 + wr * 32 + m * 16 + l15;
          af[h][m][ks] = ld_frag(&Als[cur][R * 64 + (((ks * 4 + lq) ^ asw) * 8)]);
        }
#pragma unroll
    for (int ks = 0; ks < 2; ++ks)
#pragma unroll
      for (int h = 0; h < 2; ++h)
#pragma unroll
        for (int m = 0; m < 2; ++m)
#pragma unroll
          for (int n = 0; n < 4; ++n)
            acc[h][m][n] = __builtin_amdgcn_mfma_f32_16x16x32_bf16(
                af[h][m][ks], bq[ks][n], acc[h][m][n], 0, 0, 0);
    __syncthreads();
    cur = nxt;
  }

  // epilogue: bias + silu + combine halves -> fp32 out
#pragma unroll
  for (int n = 0; n < 4; ++n) {
    const int col = d0 + wc * 64 + n * 16 + l15;
    const float b2v = b2[col];
#pragma unroll
    for (int m = 0; m < 2; ++m) {
#pragma unroll
      for (int i = 0; i < 4; ++i) {
        const int e = e0 + wr * 32 + m * 16 + lq * 4 + i;
        if (e < E_NUM) {
          out[(size_t)e * D_DIM + col] =
              silu_f(acc[0][m][n][i] + b2v) + silu_f(acc[1][m][n][i] + b2v);
        }
      }
    }
  }
}

extern "C" void kernel_launch(void* const* d_in, const int* in_sizes, int n_in,
                              void* d_out, int out_size, void* d_ws, size_t ws_size,
                              hipStream_t stream) {
  const float* node_embed = (const float*)d_in[0];
  const float* x_edge_c = (const float*)d_in[1];
  const float* ori = (const float*)d_in[2];
  const float* W1 = (const float*)d_in[3];
  const float* b1 = (const float*)d_in[4];
  const float* W2 = (const float*)d_in[5];
  const float* b2 = (const float*)d_in[6];
  float* out_p = (float*)d_out;

  char* ws = (char*)d_ws;
  short* P1 = (short*)ws;                   // [196][256][32] bf16 = 3,211,264 B
  short* P2 = (short*)(ws + 3211264);       // [8][6272][32] bf16 = 3,211,264 B
  short* hgp = (short*)(ws + 2 * 3211264);  // [8][24000][32] bf16 = 12,288,000 B

  pack_p1<<<dim3(D_DIM / 32), 256, 0, stream>>>(W1, P1);
  pack_p2<<<dim3(D_DIM / 128, 8), 128, 0, stream>>>(W2, P2);

  gemm1_kernel<<<dim3(M1 / 32), 512, 0, stream>>>(node_embed, ori, x_edge_c, P1, b1, hgp);

  gemm2_kernel<<<dim3(D_DIM / 128, (E_NUM + 63) / 64), 256, 0, stream>>>(hgp, P2, b2, out_p);
}